// Round 1
// baseline (342.527 us; speedup 1.0000x reference)
//
#include <hip/hip_runtime.h>
#include <cfloat>

// Problem geometry (fixed by reference):
//   z: (32, 256, 32, 32) f32, emb: (1024, 256) f32
//   positions P = 32*32*32 = 32768 (p = n*1024 + h*32 + w), K = 256, CODES = 1024
//   d_out = [quantized 8388608][straight_through 8388608][indices-as-float 32768]

#define P_TOTAL   32768
#define K_DIM     256
#define N_CODES   1024
#define Q_ELEMS   8388608

// round each square separately (numpy does z**2 then sums); the asm barrier
// prevents -ffp-contract=fast from fusing v*v into the following add.
__device__ __forceinline__ float sq_sep(float v) {
    float t = v * v;
    asm volatile("" : "+v"(t));
    return t;
}

// ---------------------------------------------------------------------------
// Kernel 1: zsq[p] = numpy-pairwise sum of z_p[k]^2 ; wsq[c] likewise for codes
// numpy pairwise for n=256: split 128+128; each 128: 8 accumulators, unrolled.
// ---------------------------------------------------------------------------
__global__ void k1_sums(const float* __restrict__ z, const float* __restrict__ wemb,
                        float* __restrict__ zsq, float* __restrict__ wsq) {
    const int b = blockIdx.x;
    const int tid = threadIdx.x;
    if (b < 128) {
        const int p = b * 256 + tid;
        const int n = p >> 10, hw = p & 1023;
        const float* base = z + (((size_t)(n * 256)) << 10) + hw;  // stride 1024 over k
        float half[2];
        #pragma unroll
        for (int h = 0; h < 2; ++h) {
            const float* x = base + (((size_t)(h * 128)) << 10);
            float r[8];
            #pragma unroll
            for (int j = 0; j < 8; ++j) r[j] = sq_sep(x[((size_t)j) << 10]);
            for (int i = 8; i < 128; i += 8) {
                #pragma unroll
                for (int j = 0; j < 8; ++j) r[j] += sq_sep(x[((size_t)(i + j)) << 10]);
            }
            half[h] = ((r[0] + r[1]) + (r[2] + r[3])) + ((r[4] + r[5]) + (r[6] + r[7]));
        }
        zsq[p] = half[0] + half[1];
    } else {
        const int c = (b - 128) * 256 + tid;
        const float* base = wemb + (size_t)c * 256;
        float half[2];
        #pragma unroll
        for (int h = 0; h < 2; ++h) {
            const float* x = base + h * 128;
            float r[8];
            #pragma unroll
            for (int j = 0; j < 8; ++j) r[j] = sq_sep(x[j]);
            for (int i = 8; i < 128; i += 8) {
                #pragma unroll
                for (int j = 0; j < 8; ++j) r[j] += sq_sep(x[i + j]);
            }
            half[h] = ((r[0] + r[1]) + (r[2] + r[3])) + ((r[4] + r[5]) + (r[6] + r[7]));
        }
        wsq[c] = half[0] + half[1];
    }
}

// ---------------------------------------------------------------------------
// Kernel 2: fused GEMM + argmin.
// Block: 256 threads, 64 positions (one n, 64 consecutive hw), all 1024 codes
// in 8 chunks of 128. K staged in chunks of 32. Micro-tile 4 pos x 8 codes.
// Thread (tr = tid>>4, tc = tid&15): positions tr*4..tr*4+3,
// codes {tc*4+j, 64+tc*4+j} within chunk (conflict-free b128 reads from Bs).
// d = fma(-2, dot, zsq) + wsq  (== (zsq - 2*mm) + wsq bitwise; 2*mm exact)
// argmin: strict < (first occurrence), butterfly over the 16 tc lanes with
// lower-index tie-break.
// ---------------------------------------------------------------------------
__launch_bounds__(256, 2)
__global__ void k2_argmin(const float* __restrict__ z, const float* __restrict__ wemb,
                          const float* __restrict__ zsq, const float* __restrict__ wsq,
                          float* __restrict__ idx_out) {
    __shared__ float As[32 * 64];     // [k][m], 8 KB
    __shared__ float Bs[32 * 132];    // [k][c] padded stride 132 (16B-aligned rows)
    __shared__ float wsqs[N_CODES];   // 4 KB

    const int tid = threadIdx.x;
    const int bid = blockIdx.x;
    const int tc = tid & 15;
    const int tr = tid >> 4;
    const int p0 = bid * 64;
    const int n = p0 >> 10;
    const int hw0 = p0 & 1023;
    const int w = tid >> 6, l = tid & 63;

    #pragma unroll
    for (int i = 0; i < 4; ++i) wsqs[tid + i * 256] = wsq[tid + i * 256];

    float zr[4];
    #pragma unroll
    for (int m = 0; m < 4; ++m) zr[m] = zsq[p0 + tr * 4 + m];

    float rmin[4];
    int ridx[4];
    #pragma unroll
    for (int m = 0; m < 4; ++m) { rmin[m] = FLT_MAX; ridx[m] = 0; }

    for (int cc = 0; cc < 8; ++cc) {
        float acc[4][8];
        #pragma unroll
        for (int m = 0; m < 4; ++m)
            #pragma unroll
            for (int j = 0; j < 8; ++j) acc[m][j] = 0.0f;

        for (int kc = 0; kc < 8; ++kc) {
            __syncthreads();   // previous tile's reads done before overwrite
            // ---- stage A (z tile, [k][m]): 8 floats/thread, reg->LDS ----
            #pragma unroll
            for (int j = 0; j < 2; ++j) {
                const int chunk = (j * 4 + w) * 64 + l;       // 0..511
                const int kk = chunk >> 4, m4 = chunk & 15;
                const float4 v = *(const float4*)&z[(((size_t)(n * 256 + kc * 32 + kk)) << 10) + hw0 + m4 * 4];
                *(float4*)&As[kk * 64 + m4 * 4] = v;
            }
            // ---- stage B (code tile, transposed to [k][c]) ----
            #pragma unroll
            for (int i = 0; i < 4; ++i) {
                const int cl = (tid >> 3) + i * 32;           // 0..127
                const int kq = tid & 7;                       // k-quad
                const float4 v = *(const float4*)&wemb[((size_t)(cc * 128 + cl)) * 256 + kc * 32 + kq * 4];
                Bs[(kq * 4 + 0) * 132 + cl] = v.x;
                Bs[(kq * 4 + 1) * 132 + cl] = v.y;
                Bs[(kq * 4 + 2) * 132 + cl] = v.z;
                Bs[(kq * 4 + 3) * 132 + cl] = v.w;
            }
            __syncthreads();
            // ---- 32 k-steps, sequential-k fma chains ----
            #pragma unroll
            for (int kk = 0; kk < 32; ++kk) {
                const float4 a  = *(const float4*)&As[kk * 64 + tr * 4];
                const float4 b0 = *(const float4*)&Bs[kk * 132 + tc * 4];
                const float4 b1 = *(const float4*)&Bs[kk * 132 + 64 + tc * 4];
                const float am[4] = {a.x, a.y, a.z, a.w};
                const float bb[8] = {b0.x, b0.y, b0.z, b0.w, b1.x, b1.y, b1.z, b1.w};
                #pragma unroll
                for (int m = 0; m < 4; ++m)
                    #pragma unroll
                    for (int j = 0; j < 8; ++j)
                        acc[m][j] = __builtin_fmaf(am[m], bb[j], acc[m][j]);
            }
        }
        // ---- per-chunk argmin epilogue ----
        #pragma unroll
        for (int m = 0; m < 4; ++m) {
            float bd = FLT_MAX;
            int bi = 0;
            #pragma unroll
            for (int j = 0; j < 8; ++j) {
                const int c = cc * 128 + ((j < 4) ? (tc * 4 + j) : (64 + tc * 4 + (j - 4)));
                const float d = __builtin_fmaf(-2.0f, acc[m][j], zr[m]) + wsqs[c];
                if (d < bd) { bd = d; bi = c; }   // strict <: first occurrence wins
            }
            #pragma unroll
            for (int off = 1; off < 16; off <<= 1) {
                const float od = __shfl_xor(bd, off);
                const int   oi = __shfl_xor(bi, off);
                if (od < bd || (od == bd && oi < bi)) { bd = od; bi = oi; }
            }
            if (bd < rmin[m] || (bd == rmin[m] && bi < ridx[m])) { rmin[m] = bd; ridx[m] = bi; }
        }
    }
    if (tc == 0) {
        #pragma unroll
        for (int m = 0; m < 4; ++m)
            idx_out[p0 + tr * 4 + m] = (float)ridx[m];
    }
}

// ---------------------------------------------------------------------------
// Kernel 3: gather codes + straight-through, NCHW coalesced float4 writes.
// out0[n][c][hw] = W[idx[n][hw]][c] ; out1 = (q - z) + z (faithful fp32)
// ---------------------------------------------------------------------------
__global__ void k3_gather(const float* __restrict__ z, const float* __restrict__ wemb,
                          const float* __restrict__ idxf,
                          float* __restrict__ out0, float* __restrict__ out1) {
    const int t = blockIdx.x * 256 + threadIdx.x;    // 2,097,152 threads
    const int hw4 = t & 255, c = (t >> 8) & 255, n = t >> 16;
    const size_t zo = (((size_t)(n * 256 + c)) << 10) + hw4 * 4;
    const float4 zv = *(const float4*)&z[zo];
    const float4 iv = *(const float4*)&idxf[n * 1024 + hw4 * 4];
    float4 q, st;
    {
        const int i0 = (int)iv.x; q.x = wemb[(size_t)i0 * 256 + c]; st.x = (q.x - zv.x) + zv.x;
        const int i1 = (int)iv.y; q.y = wemb[(size_t)i1 * 256 + c]; st.y = (q.y - zv.y) + zv.y;
        const int i2 = (int)iv.z; q.z = wemb[(size_t)i2 * 256 + c]; st.z = (q.z - zv.z) + zv.z;
        const int i3 = (int)iv.w; q.w = wemb[(size_t)i3 * 256 + c]; st.w = (q.w - zv.w) + zv.w;
    }
    *(float4*)&out0[zo] = q;
    *(float4*)&out1[zo] = st;
}

extern "C" void kernel_launch(void* const* d_in, const int* in_sizes, int n_in,
                              void* d_out, int out_size, void* d_ws, size_t ws_size,
                              hipStream_t stream) {
    const float* z = (const float*)d_in[0];
    const float* wemb = (const float*)d_in[1];
    float* out = (float*)d_out;
    float* out0 = out;                 // quantized
    float* out1 = out + Q_ELEMS;       // straight_through
    float* oidx = out + 2 * Q_ELEMS;   // indices (as float)
    float* zsq = (float*)d_ws;         // 32768 floats
    float* wsq = zsq + P_TOTAL;        // 1024 floats

    k1_sums<<<132, 256, 0, stream>>>(z, wemb, zsq, wsq);
    k2_argmin<<<P_TOTAL / 64, 256, 0, stream>>>(z, wemb, zsq, wsq, oidx);
    k3_gather<<<Q_ELEMS / 4 / 256, 256, 0, stream>>>(z, wemb, oidx, out0, out1);
}